// Round 10
// baseline (145.943 us; speedup 1.0000x reference)
//
#include <hip/hip_runtime.h>

constexpr int BB = 16;     // batch
constexpr int CC = 512;    // channels
constexpr int PP = 32;     // clusters
constexpr int NN = 4096;   // H*W
constexpr int TN = 64;     // n-tile per block

using f32x4 = __attribute__((ext_vector_type(4))) float;
using bf16x8 = __attribute__((ext_vector_type(8))) short;
typedef unsigned int uint;

__device__ __forceinline__ ushort f2bf(float f) {
  unsigned u = __builtin_bit_cast(unsigned, f);
  u += 0x7FFFu + ((u >> 16) & 1u);   // round-to-nearest-even
  return (ushort)(u >> 16);
}

// pack float -> (bf16_lo << 16) | bf16_hi, hi = bf16(f), lo = bf16(f - hi)
__device__ __forceinline__ uint packbf(float f) {
  uint u = __builtin_bit_cast(uint, f);
  uint hi = (u + (0x7FFFu + ((u >> 16) & 1u))) >> 16;
  float hif = __builtin_bit_cast(float, hi << 16);
  float lof = f - hif;
  uint ul = __builtin_bit_cast(uint, lof);
  uint lo = (ul + (0x7FFFu + ((ul >> 16) & 1u))) >> 16;
  return (lo << 16) | hi;
}

struct BfPair { bf16x8 hi, lo; };

__device__ __forceinline__ BfPair unpack8(const uint* __restrict__ row, int co) {
  uint4 a = *(const uint4*)(row + co);
  uint4 b = *(const uint4*)(row + co + 4);
  union { bf16x8 v; uint d[4]; } H, L;
  H.d[0] = (a.x & 0xffffu) | (a.y << 16); L.d[0] = (a.x >> 16) | (a.y & 0xffff0000u);
  H.d[1] = (a.z & 0xffffu) | (a.w << 16); L.d[1] = (a.z >> 16) | (a.w & 0xffff0000u);
  H.d[2] = (b.x & 0xffffu) | (b.y << 16); L.d[2] = (b.x >> 16) | (b.y & 0xffff0000u);
  H.d[3] = (b.z & 0xffffu) | (b.w << 16); L.d[3] = (b.z >> 16) | (b.w & 0xffff0000u);
  return {H.v, L.v};
}

// ---------------------------------------------------------------------------
// prep: beta/rbeta/csq (blocks 0..31) + zero sum_ass & both qx slices (all).
// grid 256 x 64 thr.
// ---------------------------------------------------------------------------
__global__ __launch_bounds__(64) void prep_kernel(
    const float* __restrict__ w, const float* __restrict__ sf,
    float* __restrict__ beta, float* __restrict__ rbeta,
    float* __restrict__ csq, float* __restrict__ zbuf) {
  int t = threadIdx.x;
  // zero sum_ass + qx2 (512 + 2*B*P*C floats = 131200 float4)
  float4* z4 = (float4*)zbuf;
  for (int i = blockIdx.x * 64 + t; i < 131200; i += 256 * 64)
    z4[i] = make_float4(0.f, 0.f, 0.f, 0.f);
  if (blockIdx.x < PP) {
    int p = blockIdx.x;
    float s = 0.f;
    for (int i = t; i < CC; i += 64) {
      float v = w[p * CC + i];
      s = fmaf(v, v, s);
    }
#pragma unroll
    for (int off = 32; off; off >>= 1) s += __shfl_down(s, off);
    if (t == 0) {
      csq[p] = s;
      float e = __expf(-sf[p]);
      rbeta[p] = 1.f + e;            // 1/beta
      beta[p] = 1.f / (1.f + e);     // beta
    }
  }
}

// ---------------------------------------------------------------------------
// fused assign+qx, occupancy-first: TN=64, grid 1024 (= 4 blocks/CU),
// block 256 = 4 waves, LDS 31.3 KB.
// Phase 1: cx = cent·x via split-bf16 MFMA; wave wv owns n in
//   [16wv,16wv+16), all 32 p (acc[2]). In-register softmax; assign store +
//   sum_ass atomics; assign bf16 -> abf.
// Phase 2: qx += a[p][n]·x[c][n]; x tile [128c][64n] bf16 (pitch 72,
//   aliases phase-1 xpk/cpk), 4 c-chunks; atomicAdd into 2-way-split qx.
// ---------------------------------------------------------------------------
__global__ __launch_bounds__(256, 4) void fused_kernel(
    const float* __restrict__ x, const float* __restrict__ w,
    const float* __restrict__ rbeta_, const float* __restrict__ csq_,
    float* __restrict__ assign_out, float* __restrict__ sum_ass,
    float* __restrict__ qx2) {
  __shared__ uint shbuf[6528];        // 26112 B: xpk[64][68] + cpk[32][68]
  __shared__ ushort abf[PP][72];      // assign bf16, 4.6 KB
  __shared__ float xsqw[4][4][16];    // per-wave xsq partials, 1 KB
  __shared__ float xsqf[TN];          // xsq per n, 256 B

  uint(*xpk)[68] = (uint(*)[68])shbuf;            // phase1 [n][c] packed
  uint(*cpk)[68] = (uint(*)[68])(shbuf + 64 * 68);  // phase1 [p][c] packed
  ushort(*xt)[72] = (ushort(*)[72])shbuf;         // phase2 [c][n] bf16 alias

  int tid = threadIdx.x;
  int wv = tid >> 6, lane = tid & 63;
  int l15 = lane & 15, lg = lane >> 4;
  int b = blockIdx.x >> 6;
  int n0 = (blockIdx.x & 63) * TN;

  int c_s = tid >> 2;          // phase1 staging c row 0..63
  int nw = (tid & 3) << 4;     // phase1 staging n window (16 n)
  int p_s = tid >> 3;          // centers staging p 0..31
  int cq8 = (tid & 7) << 3;    // centers staging c offset 0..56

  const float* xb = x + (size_t)b * CC * NN + n0 + nw;
  const float* wb = w + (size_t)p_s * CC + cq8;

  f32x4 acc[2];
  acc[0] = {0.f, 0.f, 0.f, 0.f};
  acc[1] = {0.f, 0.f, 0.f, 0.f};
  float sq[16];
#pragma unroll
  for (int i = 0; i < 16; ++i) sq[i] = 0.f;

  float4 xr[4], wr0, wr1;
  // ---- phase 1 prologue: load + stage chunk 0
#pragma unroll
  for (int i = 0; i < 4; ++i)
    xr[i] = *(const float4*)&xb[(size_t)c_s * NN + i * 4];
  wr0 = *(const float4*)&wb[0];
  wr1 = *(const float4*)&wb[4];
#pragma unroll
  for (int i = 0; i < 4; ++i) {
    float4 v = xr[i];
    sq[4 * i + 0] = fmaf(v.x, v.x, sq[4 * i + 0]);
    sq[4 * i + 1] = fmaf(v.y, v.y, sq[4 * i + 1]);
    sq[4 * i + 2] = fmaf(v.z, v.z, sq[4 * i + 2]);
    sq[4 * i + 3] = fmaf(v.w, v.w, sq[4 * i + 3]);
    int nr = nw + i * 4;
    xpk[nr + 0][c_s] = packbf(v.x);
    xpk[nr + 1][c_s] = packbf(v.y);
    xpk[nr + 2][c_s] = packbf(v.z);
    xpk[nr + 3][c_s] = packbf(v.w);
  }
  {
    uint4 u0 = {packbf(wr0.x), packbf(wr0.y), packbf(wr0.z), packbf(wr0.w)};
    uint4 u1 = {packbf(wr1.x), packbf(wr1.y), packbf(wr1.z), packbf(wr1.w)};
    *(uint4*)&cpk[p_s][cq8] = u0;
    *(uint4*)&cpk[p_s][cq8 + 4] = u1;
  }
  __syncthreads();

  // ---- phase 1 main loop over 8 c-chunks of 64
  for (int c0 = 0; c0 < CC; c0 += 64) {
    bool more = (c0 + 64 < CC);
    if (more) {
#pragma unroll
      for (int i = 0; i < 4; ++i)
        xr[i] = *(const float4*)&xb[(size_t)(c0 + 64 + c_s) * NN + i * 4];
      wr0 = *(const float4*)&wb[c0 + 64];
      wr1 = *(const float4*)&wb[c0 + 64 + 4];
    }
#pragma unroll
    for (int ks = 0; ks < 2; ++ks) {
      int co = ks * 32 + lg * 8;
      BfPair A0 = unpack8(&cpk[l15][0], co);
      BfPair A1 = unpack8(&cpk[l15 + 16][0], co);
      BfPair B0 = unpack8(&xpk[wv * 16 + l15][0], co);
      acc[0] = __builtin_amdgcn_mfma_f32_16x16x32_bf16(A0.hi, B0.hi, acc[0], 0, 0, 0);
      acc[1] = __builtin_amdgcn_mfma_f32_16x16x32_bf16(A1.hi, B0.hi, acc[1], 0, 0, 0);
      acc[0] = __builtin_amdgcn_mfma_f32_16x16x32_bf16(A0.hi, B0.lo, acc[0], 0, 0, 0);
      acc[1] = __builtin_amdgcn_mfma_f32_16x16x32_bf16(A1.hi, B0.lo, acc[1], 0, 0, 0);
      acc[0] = __builtin_amdgcn_mfma_f32_16x16x32_bf16(A0.lo, B0.hi, acc[0], 0, 0, 0);
      acc[1] = __builtin_amdgcn_mfma_f32_16x16x32_bf16(A1.lo, B0.hi, acc[1], 0, 0, 0);
    }
    if (more) {
      __syncthreads();
#pragma unroll
      for (int i = 0; i < 4; ++i) {
        float4 v = xr[i];
        sq[4 * i + 0] = fmaf(v.x, v.x, sq[4 * i + 0]);
        sq[4 * i + 1] = fmaf(v.y, v.y, sq[4 * i + 1]);
        sq[4 * i + 2] = fmaf(v.z, v.z, sq[4 * i + 2]);
        sq[4 * i + 3] = fmaf(v.w, v.w, sq[4 * i + 3]);
        int nr = nw + i * 4;
        xpk[nr + 0][c_s] = packbf(v.x);
        xpk[nr + 1][c_s] = packbf(v.y);
        xpk[nr + 2][c_s] = packbf(v.z);
        xpk[nr + 3][c_s] = packbf(v.w);
      }
      uint4 u0 = {packbf(wr0.x), packbf(wr0.y), packbf(wr0.z), packbf(wr0.w)};
      uint4 u1 = {packbf(wr1.x), packbf(wr1.y), packbf(wr1.z), packbf(wr1.w)};
      *(uint4*)&cpk[p_s][cq8] = u0;
      *(uint4*)&cpk[p_s][cq8 + 4] = u1;
      __syncthreads();
    }
  }

  // ---- xsq reduce: sum over this wave's 16 c-rows (lane bits 2..5)
#pragma unroll
  for (int i = 0; i < 16; ++i) {
    sq[i] += __shfl_xor(sq[i], 4);
    sq[i] += __shfl_xor(sq[i], 8);
    sq[i] += __shfl_xor(sq[i], 16);
    sq[i] += __shfl_xor(sq[i], 32);
  }
  if (lane < 4) {
#pragma unroll
    for (int i = 0; i < 16; ++i) xsqw[wv][lane][i] = sq[i];
  }
  __syncthreads();   // phase-1 LDS reads complete past here
  if (tid < TN)
    xsqf[tid] = xsqw[0][tid >> 4][tid & 15] + xsqw[1][tid >> 4][tid & 15] +
                xsqw[2][tid >> 4][tid & 15] + xsqw[3][tid >> 4][tid & 15];
  __syncthreads();

  float xsqn = xsqf[wv * 16 + l15];

  // logits + in-register softmax over p (shfl_xor 16/32 spans lg groups)
  float L[2][4];
  float m = -3.4e38f;
#pragma unroll
  for (int pf = 0; pf < 2; ++pf)
#pragma unroll
    for (int i = 0; i < 4; ++i) {
      int p = pf * 16 + lg * 4 + i;
      float l = fminf(2.f * acc[pf][i] - xsqn - csq_[p], 0.f) * rbeta_[p];
      L[pf][i] = l;
      m = fmaxf(m, l);
    }
  m = fmaxf(m, __shfl_xor(m, 16));
  m = fmaxf(m, __shfl_xor(m, 32));
  float s = 0.f;
#pragma unroll
  for (int pf = 0; pf < 2; ++pf)
#pragma unroll
    for (int i = 0; i < 4; ++i) {
      float e = __expf(L[pf][i] - m);
      L[pf][i] = e;
      s += e;
    }
  s += __shfl_xor(s, 16);
  s += __shfl_xor(s, 32);
  float inv = 1.f / s;

  // assign store + abf bf16 + fused sum_ass
  int nl = wv * 16 + l15;
  float* aoB = assign_out + (size_t)b * PP * NN + n0 + nl;
#pragma unroll
  for (int pf = 0; pf < 2; ++pf)
#pragma unroll
    for (int i = 0; i < 4; ++i) {
      int p = pf * 16 + lg * 4 + i;
      float a = L[pf][i] * inv;
      aoB[(size_t)p * NN] = a;
      abf[p][nl] = f2bf(a);
      float v = a;
      v += __shfl_xor(v, 1); v += __shfl_xor(v, 2);
      v += __shfl_xor(v, 4); v += __shfl_xor(v, 8);
      if (l15 == 0) atomicAdd(&sum_ass[b * PP + p], v);
    }

  // ---- phase 2: qx += a[p][n] * x[c][n] over this tile's 64 n.
  int c_s2 = tid >> 1;            // x tile row 0..127
  int nh2 = (tid & 1) << 5;       // n half 0/32
  const float* xg = x + (size_t)b * CC * NN + n0;
  float* qxp = qx2 + (size_t)(blockIdx.x & 1) * BB * PP * CC;

  for (int ch = 0; ch < 4; ++ch) {   // c-chunks of 128
    __syncthreads();   // abf writers / previous chunk readers done
    {
      float4 v[8];
#pragma unroll
      for (int i = 0; i < 8; ++i)
        v[i] = *(const float4*)&xg[(size_t)(ch * 128 + c_s2) * NN + nh2 + i * 4];
#pragma unroll
      for (int i = 0; i < 8; ++i) {
        ushort4 u;
        u.x = f2bf(v[i].x); u.y = f2bf(v[i].y);
        u.z = f2bf(v[i].z); u.w = f2bf(v[i].w);
        *(ushort4*)&xt[c_s2][nh2 + i * 4] = u;
      }
    }
    __syncthreads();

    f32x4 q2[2][2];
#pragma unroll
    for (int pf = 0; pf < 2; ++pf)
#pragma unroll
      for (int cf = 0; cf < 2; ++cf) q2[pf][cf] = {0.f, 0.f, 0.f, 0.f};
#pragma unroll
    for (int ks = 0; ks < 2; ++ks) {
      int ko = ks * 32 + lg * 8;
      bf16x8 A0 = *(const bf16x8*)&abf[l15][ko];
      bf16x8 A1 = *(const bf16x8*)&abf[l15 + 16][ko];
#pragma unroll
      for (int cf = 0; cf < 2; ++cf) {
        bf16x8 Bv = *(const bf16x8*)&xt[wv * 32 + cf * 16 + l15][ko];
        q2[0][cf] = __builtin_amdgcn_mfma_f32_16x16x32_bf16(A0, Bv, q2[0][cf], 0, 0, 0);
        q2[1][cf] = __builtin_amdgcn_mfma_f32_16x16x32_bf16(A1, Bv, q2[1][cf], 0, 0, 0);
      }
    }
#pragma unroll
    for (int pf = 0; pf < 2; ++pf)
#pragma unroll
      for (int cf = 0; cf < 2; ++cf)
#pragma unroll
        for (int i = 0; i < 4; ++i) {
          int p = pf * 16 + lg * 4 + i;
          int c = ch * 128 + wv * 32 + cf * 16 + l15;
          atomicAdd(&qxp[((size_t)b * PP + p) * CC + c], q2[pf][cf][i]);
        }
  }
}

// ---------------------------------------------------------------------------
// finalize: qx = slice0 + slice1; out = (qx/max(sa,1e-5) - centers)/sigma;
// L2-normalize over c; write transposed out_t[b][c][p].
// ---------------------------------------------------------------------------
__global__ __launch_bounds__(256) void finalize_kernel(
    const float* __restrict__ qx2, const float* __restrict__ w,
    const float* __restrict__ beta, const float* __restrict__ sum_ass,
    float* __restrict__ out_t) {
  int b = blockIdx.x >> 5;
  int p = blockIdx.x & 31;
  int tid = threadIdx.x;
  int wave = tid >> 6, lane = tid & 63;

  float inv_sa = 1.f / fmaxf(sum_ass[b * PP + p], 1e-5f);
  float rsig = rsqrtf(0.5f * beta[p]);

  int c0 = tid, c1 = tid + 256;
  const float* r0 = qx2 + ((size_t)b * PP + p) * CC;
  const float* r1 = r0 + (size_t)BB * PP * CC;
  float q0 = r0[c0] + r1[c0];
  float q1 = r0[c1] + r1[c1];
  const float* wrow = w + (size_t)p * CC;
  float t0 = (q0 * inv_sa - wrow[c0]) * rsig;
  float t1 = (q1 * inv_sa - wrow[c1]) * rsig;

  float nr = t0 * t0 + t1 * t1;
#pragma unroll
  for (int off = 32; off; off >>= 1) nr += __shfl_down(nr, off);
  __shared__ float red[4];
  if (lane == 0) red[wave] = nr;
  __syncthreads();
  float norm2 = red[0] + red[1] + red[2] + red[3];
  float scale = 1.f / fmaxf(sqrtf(norm2), 1e-12f);

  float* ob = out_t + (size_t)b * CC * PP + p;
  ob[(size_t)c0 * PP] = t0 * scale;
  ob[(size_t)c1 * PP] = t1 * scale;
}

// ---------------------------------------------------------------------------
extern "C" void kernel_launch(void* const* d_in, const int* in_sizes, int n_in,
                              void* d_out, int out_size, void* d_ws,
                              size_t ws_size, hipStream_t stream) {
  const float* x = (const float*)d_in[0];   // [B,C,H,W]
  const float* w = (const float*)d_in[1];   // [P,C,1,1]
  const float* sf = (const float*)d_in[2];  // [P]

  float* out_t = (float*)d_out;                  // [B,C,P]
  float* assign = out_t + (size_t)BB * CC * PP;  // [B,P,N]

  float* ws = (float*)d_ws;
  float* beta = ws;           // 32
  float* rbeta = ws + 32;     // 32
  float* csq = ws + 64;       // 32
  float* sum_ass = ws + 96;   // 512 (zbuf starts here)
  float* qx2 = ws + 608;      // 2 * B*P*C = 524288 floats (2 MB)

  prep_kernel<<<256, 64, 0, stream>>>(w, sf, beta, rbeta, csq, sum_ass);
  fused_kernel<<<BB * 64, 256, 0, stream>>>(x, w, rbeta, csq, assign,
                                            sum_ass, qx2);
  finalize_kernel<<<BB * PP, 256, 0, stream>>>(qx2, w, beta, sum_ass, out_t);
}

// Round 11
// 85.657 us; speedup vs baseline: 1.7038x; 1.7038x over previous
//
#include <hip/hip_runtime.h>

constexpr int BB = 16;     // batch
constexpr int CC = 512;    // channels
constexpr int PP = 32;     // clusters
constexpr int NN = 4096;   // H*W

using f32x4 = __attribute__((ext_vector_type(4))) float;
using bf16x8 = __attribute__((ext_vector_type(8))) short;
typedef unsigned int uint;

__device__ __forceinline__ ushort f2bf(float f) {
  unsigned u = __builtin_bit_cast(unsigned, f);
  u += 0x7FFFu + ((u >> 16) & 1u);   // round-to-nearest-even
  return (ushort)(u >> 16);
}

// ---------------------------------------------------------------------------
// prep: beta/rbeta/csq; zero sum_ass; split centers into bf16 hi/lo planes
// chi/clo [32][512] (row-major, 16B-aligned fragment rows).
// grid 32 (p), block 64.
// ---------------------------------------------------------------------------
__global__ __launch_bounds__(64) void prep_kernel(
    const float* __restrict__ w, const float* __restrict__ sf,
    float* __restrict__ beta, float* __restrict__ rbeta,
    float* __restrict__ csq, float* __restrict__ sum_ass,
    ushort* __restrict__ chi, ushort* __restrict__ clo) {
  int p = blockIdx.x;
  int t = threadIdx.x;
  if (t < 16) sum_ass[p * 16 + t] = 0.f;
  float s = 0.f;
  int c8 = t * 8;
  float4 v0 = *(const float4*)&w[p * CC + c8];
  float4 v1 = *(const float4*)&w[p * CC + c8 + 4];
  ushort h[8], l[8];
  float vv[8] = {v0.x, v0.y, v0.z, v0.w, v1.x, v1.y, v1.z, v1.w};
#pragma unroll
  for (int i = 0; i < 8; ++i) {
    s = fmaf(vv[i], vv[i], s);
    h[i] = f2bf(vv[i]);
    float hf = __builtin_bit_cast(float, (uint)h[i] << 16);
    l[i] = f2bf(vv[i] - hf);
  }
  *(ushort4*)&chi[p * CC + c8] = make_ushort4(h[0], h[1], h[2], h[3]);
  *(ushort4*)&chi[p * CC + c8 + 4] = make_ushort4(h[4], h[5], h[6], h[7]);
  *(ushort4*)&clo[p * CC + c8] = make_ushort4(l[0], l[1], l[2], l[3]);
  *(ushort4*)&clo[p * CC + c8 + 4] = make_ushort4(l[4], l[5], l[6], l[7]);
#pragma unroll
  for (int off = 32; off; off >>= 1) s += __shfl_down(s, off);
  if (t == 0) {
    csq[p] = s;
    float e = __expf(-sf[p]);
    rbeta[p] = 1.f + e;            // 1/beta
    beta[p] = 1.f / (1.f + e);     // beta
  }
}

// ---------------------------------------------------------------------------
// assign, barrier-free fragment-direct: cx[p][n] = sum_c cent[p][c]*x[c][n]
// via split-bf16 MFMA (hi*hi + hi*lo + lo*hi).
// grid 512 (16 b x 32 tiles of 128 n), block 256 = 4 independent waves,
// wave wv owns n in [n0+32wv, n0+32wv+32) (2 B-frags), all 32 p (2 A-frags).
// B-frags loaded DIRECTLY from global x (8 stride-N dwords each, packed to
// hi/lo in registers); A-frags from prep's chi/clo planes (L2-resident).
// No LDS, no barriers. Softmax + xsq fully in-register (shfl over lg).
// ---------------------------------------------------------------------------
__global__ __launch_bounds__(256) void assign_kernel(
    const float* __restrict__ x, const ushort* __restrict__ chi,
    const ushort* __restrict__ clo, const float* __restrict__ rbeta_,
    const float* __restrict__ csq_, float* __restrict__ assign_out,
    float* __restrict__ sum_ass) {
  int tid = threadIdx.x;
  int wv = tid >> 6, lane = tid & 63;
  int l15 = lane & 15, lg = lane >> 4;
  int b = blockIdx.x >> 5;
  int n0 = (blockIdx.x & 31) * 128 + wv * 32;

  const float* xb = x + (size_t)b * CC * NN + n0 + l15;

  f32x4 acc[2][2];   // [pf][nf]
#pragma unroll
  for (int i = 0; i < 2; ++i)
#pragma unroll
    for (int j = 0; j < 2; ++j) acc[i][j] = {0.f, 0.f, 0.f, 0.f};
  float xsq[2] = {0.f, 0.f};

#pragma unroll 4
  for (int ks = 0; ks < 16; ++ks) {
    int c0 = ks * 32 + lg * 8;
    // A fragments (centers hi/lo), 16B each
    bf16x8 Ah0 = *(const bf16x8*)&chi[l15 * CC + c0];
    bf16x8 Ah1 = *(const bf16x8*)&chi[(l15 + 16) * CC + c0];
    bf16x8 Al0 = *(const bf16x8*)&clo[l15 * CC + c0];
    bf16x8 Al1 = *(const bf16x8*)&clo[(l15 + 16) * CC + c0];
#pragma unroll
    for (int nf = 0; nf < 2; ++nf) {
      // B fragment: x[c0+j][n], j=0..7, direct from global
      float xv[8];
#pragma unroll
      for (int j = 0; j < 8; ++j)
        xv[j] = xb[(size_t)(c0 + j) * NN + nf * 16];
      union { bf16x8 v; ushort e[8]; } Bh, Bl;
#pragma unroll
      for (int j = 0; j < 8; ++j) {
        xsq[nf] = fmaf(xv[j], xv[j], xsq[nf]);
        ushort h = f2bf(xv[j]);
        float hf = __builtin_bit_cast(float, (uint)h << 16);
        Bh.e[j] = h;
        Bl.e[j] = f2bf(xv[j] - hf);
      }
      acc[0][nf] = __builtin_amdgcn_mfma_f32_16x16x32_bf16(Ah0, Bh.v, acc[0][nf], 0, 0, 0);
      acc[1][nf] = __builtin_amdgcn_mfma_f32_16x16x32_bf16(Ah1, Bh.v, acc[1][nf], 0, 0, 0);
      acc[0][nf] = __builtin_amdgcn_mfma_f32_16x16x32_bf16(Ah0, Bl.v, acc[0][nf], 0, 0, 0);
      acc[1][nf] = __builtin_amdgcn_mfma_f32_16x16x32_bf16(Ah1, Bl.v, acc[1][nf], 0, 0, 0);
      acc[0][nf] = __builtin_amdgcn_mfma_f32_16x16x32_bf16(Al0, Bh.v, acc[0][nf], 0, 0, 0);
      acc[1][nf] = __builtin_amdgcn_mfma_f32_16x16x32_bf16(Al1, Bh.v, acc[1][nf], 0, 0, 0);
    }
  }

  // xsq: reduce over the 4 lg groups (each covered a disjoint c slice)
#pragma unroll
  for (int nf = 0; nf < 2; ++nf) {
    xsq[nf] += __shfl_xor(xsq[nf], 16);
    xsq[nf] += __shfl_xor(xsq[nf], 32);
  }

  // per-lane p constants
  float csqv[2][4], rbv[2][4];
#pragma unroll
  for (int pf = 0; pf < 2; ++pf)
#pragma unroll
    for (int i = 0; i < 4; ++i) {
      int p = pf * 16 + lg * 4 + i;
      csqv[pf][i] = csq_[p];
      rbv[pf][i] = rbeta_[p];
    }

  // logits + in-register softmax over p (p spans regs x lg groups)
  float L[2][2][4];   // [pf][nf][i]
  float m[2] = {-3.4e38f, -3.4e38f};
#pragma unroll
  for (int pf = 0; pf < 2; ++pf)
#pragma unroll
    for (int nf = 0; nf < 2; ++nf)
#pragma unroll
      for (int i = 0; i < 4; ++i) {
        float l = fminf(2.f * acc[pf][nf][i] - xsq[nf] - csqv[pf][i], 0.f) * rbv[pf][i];
        L[pf][nf][i] = l;
        m[nf] = fmaxf(m[nf], l);
      }
#pragma unroll
  for (int nf = 0; nf < 2; ++nf) {
    m[nf] = fmaxf(m[nf], __shfl_xor(m[nf], 16));
    m[nf] = fmaxf(m[nf], __shfl_xor(m[nf], 32));
  }
  float s[2] = {0.f, 0.f};
#pragma unroll
  for (int pf = 0; pf < 2; ++pf)
#pragma unroll
    for (int nf = 0; nf < 2; ++nf)
#pragma unroll
      for (int i = 0; i < 4; ++i) {
        float e = __expf(L[pf][nf][i] - m[nf]);
        L[pf][nf][i] = e;
        s[nf] += e;
      }
#pragma unroll
  for (int nf = 0; nf < 2; ++nf) {
    s[nf] += __shfl_xor(s[nf], 16);
    s[nf] += __shfl_xor(s[nf], 32);
    s[nf] = 1.f / s[nf];
  }

  // store assign + fused sum_ass
  float* aoB = assign_out + (size_t)b * PP * NN + n0 + l15;
#pragma unroll
  for (int pf = 0; pf < 2; ++pf)
#pragma unroll
    for (int i = 0; i < 4; ++i) {
      int p = pf * 16 + lg * 4 + i;
      float a0 = L[pf][0][i] * s[0];
      float a1 = L[pf][1][i] * s[1];
      aoB[(size_t)p * NN] = a0;
      aoB[(size_t)p * NN + 16] = a1;
      float v = a0 + a1;
      v += __shfl_xor(v, 1); v += __shfl_xor(v, 2);
      v += __shfl_xor(v, 4); v += __shfl_xor(v, 8);
      if (l15 == 0) atomicAdd(&sum_ass[b * PP + p], v);
    }
}

// ---------------------------------------------------------------------------
// qx via bf16 MFMA, k-split owned partial stores (R7 version, proven):
// qx_part[kc][b][p][c] = sum_{n in chunk} a[p][n]*x[c][n].
// grid (32 = 8 kchunks x 4 ctiles, 16 b), block 256 = 4 waves.
// ---------------------------------------------------------------------------
__global__ __launch_bounds__(256) void qx_kernel(
    const float* __restrict__ x, const float* __restrict__ assign,
    float* __restrict__ qx_part) {
  __shared__ ushort xbf[128][136];  // [c_local][n_local] bf16, 34.8 KB
  __shared__ ushort abf[32][136];   // [p][n_local] bf16, 8.7 KB

  int tid = threadIdx.x;
  int b = blockIdx.y;
  int kc = blockIdx.x >> 2;   // 0..7: k-chunk of 512 n
  int ct = blockIdx.x & 3;    // 0..3: c-tile of 128
  int wv = tid >> 6, lane = tid & 63;
  int l15 = lane & 15, lg = lane >> 4;

  const float* xb = x + ((size_t)b * CC + ct * 128) * NN + kc * 512;
  const float* ab = assign + (size_t)b * PP * NN + kc * 512;

  int c_s = tid >> 1;            // x staging row 0..127
  int nh  = (tid & 1) << 6;      // n half: 0 or 64
  int p_s = tid >> 3;            // a staging p 0..31
  int na  = (tid & 7) << 4;      // a staging n off 0..112

  f32x4 acc[2][2];
#pragma unroll
  for (int i = 0; i < 2; ++i)
#pragma unroll
    for (int j = 0; j < 2; ++j) acc[i][j] = {0.f, 0.f, 0.f, 0.f};

  for (int ch = 0; ch < 4; ++ch) {   // 4 inner chunks of 128 n
    int nb = ch * 128;
    if (ch) __syncthreads();
#pragma unroll
    for (int h = 0; h < 2; ++h) {
      float4 v[8];
#pragma unroll
      for (int i = 0; i < 8; ++i)
        v[i] = *(const float4*)&xb[(size_t)c_s * NN + nb + nh + h * 32 + i * 4];
#pragma unroll
      for (int i = 0; i < 8; ++i) {
        ushort4 u;
        u.x = f2bf(v[i].x); u.y = f2bf(v[i].y);
        u.z = f2bf(v[i].z); u.w = f2bf(v[i].w);
        *(ushort4*)&xbf[c_s][nh + h * 32 + i * 4] = u;
      }
    }
    {
      float4 v[4];
#pragma unroll
      for (int i = 0; i < 4; ++i)
        v[i] = *(const float4*)&ab[(size_t)p_s * NN + nb + na + i * 4];
#pragma unroll
      for (int i = 0; i < 4; ++i) {
        ushort4 u;
        u.x = f2bf(v[i].x); u.y = f2bf(v[i].y);
        u.z = f2bf(v[i].z); u.w = f2bf(v[i].w);
        *(ushort4*)&abf[p_s][na + i * 4] = u;
      }
    }
    __syncthreads();
#pragma unroll
    for (int ks = 0; ks < 4; ++ks) {
      int nf = ks * 32 + lg * 8;
      bf16x8 a0 = *(const bf16x8*)&abf[l15][nf];
      bf16x8 a1 = *(const bf16x8*)&abf[16 + l15][nf];
      bf16x8 b0 = *(const bf16x8*)&xbf[wv * 32 + l15][nf];
      bf16x8 b1 = *(const bf16x8*)&xbf[wv * 32 + 16 + l15][nf];
      acc[0][0] = __builtin_amdgcn_mfma_f32_16x16x32_bf16(a0, b0, acc[0][0], 0, 0, 0);
      acc[0][1] = __builtin_amdgcn_mfma_f32_16x16x32_bf16(a0, b1, acc[0][1], 0, 0, 0);
      acc[1][0] = __builtin_amdgcn_mfma_f32_16x16x32_bf16(a1, b0, acc[1][0], 0, 0, 0);
      acc[1][1] = __builtin_amdgcn_mfma_f32_16x16x32_bf16(a1, b1, acc[1][1], 0, 0, 0);
    }
  }

#pragma unroll
  for (int pf = 0; pf < 2; ++pf)
#pragma unroll
    for (int cf = 0; cf < 2; ++cf)
#pragma unroll
      for (int i = 0; i < 4; ++i) {
        int p = pf * 16 + lg * 4 + i;
        int c = ct * 128 + wv * 32 + cf * 16 + l15;
        qx_part[(((size_t)kc * BB + b) * PP + p) * CC + c] = acc[pf][cf][i];
      }
}

// ---------------------------------------------------------------------------
// finalize: qx = sum_kc qx_part; out = (qx/max(sa,1e-5) - centers)/sigma;
// L2-normalize over c; write transposed out_t[b][c][p].
// ---------------------------------------------------------------------------
__global__ __launch_bounds__(256) void finalize_kernel(
    const float* __restrict__ qx_part, const float* __restrict__ w,
    const float* __restrict__ beta, const float* __restrict__ sum_ass,
    float* __restrict__ out_t) {
  int b = blockIdx.x >> 5;
  int p = blockIdx.x & 31;
  int tid = threadIdx.x;
  int wave = tid >> 6, lane = tid & 63;

  float inv_sa = 1.f / fmaxf(sum_ass[b * PP + p], 1e-5f);
  float rsig = rsqrtf(0.5f * beta[p]);

  int c0 = tid, c1 = tid + 256;
  float q0 = 0.f, q1 = 0.f;
#pragma unroll
  for (int kc = 0; kc < 8; ++kc) {
    const float* row = qx_part + (((size_t)kc * BB + b) * PP + p) * CC;
    q0 += row[c0];
    q1 += row[c1];
  }
  const float* wrow = w + (size_t)p * CC;
  float t0 = (q0 * inv_sa - wrow[c0]) * rsig;
  float t1 = (q1 * inv_sa - wrow[c1]) * rsig;

  float nr = t0 * t0 + t1 * t1;
#pragma unroll
  for (int off = 32; off; off >>= 1) nr += __shfl_down(nr, off);
  __shared__ float red[4];
  if (lane == 0) red[wave] = nr;
  __syncthreads();
  float norm2 = red[0] + red[1] + red[2] + red[3];
  float scale = 1.f / fmaxf(sqrtf(norm2), 1e-12f);

  float* ob = out_t + (size_t)b * CC * PP + p;
  ob[(size_t)c0 * PP] = t0 * scale;
  ob[(size_t)c1 * PP] = t1 * scale;
}

// ---------------------------------------------------------------------------
extern "C" void kernel_launch(void* const* d_in, const int* in_sizes, int n_in,
                              void* d_out, int out_size, void* d_ws,
                              size_t ws_size, hipStream_t stream) {
  const float* x = (const float*)d_in[0];   // [B,C,H,W]
  const float* w = (const float*)d_in[1];   // [P,C,1,1]
  const float* sf = (const float*)d_in[2];  // [P]

  float* out_t = (float*)d_out;                  // [B,C,P]
  float* assign = out_t + (size_t)BB * CC * PP;  // [B,P,N]

  float* ws = (float*)d_ws;
  float* beta = ws;           // 32
  float* rbeta = ws + 32;     // 32
  float* csq = ws + 64;       // 32
  float* sum_ass = ws + 96;   // 512
  float* qx_part = ws + 608;  // 8 * B*P*C = 2,097,152 floats
  ushort* chi = (ushort*)(ws + 608 + 2097152);   // [32][512] bf16 hi
  ushort* clo = chi + PP * CC;                   // [32][512] bf16 lo

  prep_kernel<<<PP, 64, 0, stream>>>(w, sf, beta, rbeta, csq, sum_ass,
                                     chi, clo);
  assign_kernel<<<512, 256, 0, stream>>>(x, chi, clo, rbeta, csq, assign,
                                         sum_ass);
  qx_kernel<<<dim3(32, BB), 256, 0, stream>>>(x, assign, qx_part);
  finalize_kernel<<<BB * PP, 256, 0, stream>>>(qx_part, w, beta, sum_ass,
                                               out_t);
}